// Round 9
// baseline (179.455 us; speedup 1.0000x reference)
//
#include <hip/hip_runtime.h>
#include <math.h>

#define NFM_B 16384
#define NFM_F 39
#define NFM_E 16
#define NFM_H 200
#define TR    8           // rows per block (MFMA M=16 tile, rows 8..15 zero)
#define KPAD  232         // padded K row stride (shorts); 464B, 16B-aligned
#define NT    13          // n-tiles of 16 (208 >= 200)
#define VOCAB 1000000
#define WSCALE  64.0f     // w,v stored as fp8(x*64): lifts N(0,0.01) into e4m3 range
#define WISCALE (1.0f / 64.0f)
#define FMSC    (1.0f / 4096.0f)   // fm computed in (x64)^2 domain

typedef short short8   __attribute__((ext_vector_type(8)));   // 8 bf16 = 4 VGPRs
typedef short short4_t __attribute__((ext_vector_type(4)));
typedef float floatx4  __attribute__((ext_vector_type(4)));
typedef unsigned int uint4_t __attribute__((ext_vector_type(4)));

__device__ __forceinline__ short f2bf(float x) {   // fp32 -> bf16 RNE
    union { float f; unsigned u; } a; a.f = x;
    unsigned r = a.u + 0x7FFF + ((a.u >> 16) & 1);
    return (short)(r >> 16);
}

// fp8 e4m3fn (OCP): 1-4-3, bias 7, max 448, no inf  (encoder, RNE)
__device__ __forceinline__ unsigned char f_to_fp8(float x) {
    union { float f; unsigned u; } a; a.f = fabsf(x);
    const unsigned s = (x < 0.f) ? 0x80u : 0u;
    int e = (int)((a.u >> 23) & 255) - 127;
    if (a.f == 0.f) return (unsigned char)s;
    if (e < -6) {                          // subnormal target: quantum 2^-9
        int m = (int)rintf(a.f * 512.f);   // RNE
        if (m >= 8) return (unsigned char)(s | (1u << 3));
        return (unsigned char)(s | (unsigned)m);
    }
    unsigned m23 = a.u & 0x7FFFFF;
    unsigned m3  = m23 >> 20, rem = m23 & 0xFFFFF;
    if (rem > 0x80000 || (rem == 0x80000 && (m3 & 1))) m3++;
    if (m3 == 8) { m3 = 0; e++; }
    if (e > 8) { e = 8; m3 = 6; }          // clamp to 448
    return (unsigned char)(s | ((unsigned)(e + 7) << 3) | m3);
}
__device__ __forceinline__ float fp8_sw_decode(unsigned char b) {
    const unsigned s = (b >> 7) & 1, e = (b >> 3) & 15, m = b & 7;
    union { unsigned u; float f; } a;
    if (e == 0) { a.f = (float)m * 0.001953125f; }
    else        { a.u = ((e - 7 + 127) << 23) | (m << 20); }
    if (s) a.f = -a.f;
    return a.f;
}

// decode all 4 fp8 bytes of a dword; sel must be a literal constant for the builtin
#if defined(__has_builtin) && __has_builtin(__builtin_amdgcn_cvt_f32_fp8)
__device__ __forceinline__ floatx4 cvt4_fp8(unsigned dw) {
    floatx4 r;
    r[0] = __builtin_amdgcn_cvt_f32_fp8((int)dw, 0);
    r[1] = __builtin_amdgcn_cvt_f32_fp8((int)dw, 1);
    r[2] = __builtin_amdgcn_cvt_f32_fp8((int)dw, 2);
    r[3] = __builtin_amdgcn_cvt_f32_fp8((int)dw, 3);
    return r;
}
__device__ __forceinline__ float cvt1_fp8(unsigned char b) {
    return __builtin_amdgcn_cvt_f32_fp8((int)(unsigned)b, 0);
}
#else
__device__ __forceinline__ floatx4 cvt4_fp8(unsigned dw) {
    floatx4 r;
    r[0] = fp8_sw_decode((unsigned char)(dw));
    r[1] = fp8_sw_decode((unsigned char)(dw >> 8));
    r[2] = fp8_sw_decode((unsigned char)(dw >> 16));
    r[3] = fp8_sw_decode((unsigned char)(dw >> 24));
    return r;
}
__device__ __forceinline__ float cvt1_fp8(unsigned char b) {
    return fp8_sw_decode(b);
}
#endif

// d_ws layout (bytes):
//   [0, 16,000,000)            : v table as fp8 e4m3 of (v*64), [VOCAB][16]
//   [16,000,000, 17,000,000)   : w table as fp8 e4m3 of (w*64)
//   [17,000,000, +2*WS_FRAGS)  : W0/W1/W2 bf16 B-fragments (shorts)
#define V8_BYTES  (VOCAB * NFM_E)           // 16,000,000
#define W8_BYTE_OFF V8_BYTES
#define FRAG_BYTE_OFF (V8_BYTES + VOCAB)    // 17,000,000 (16B-aligned)
#define W0F_OFF  0
#define W0F_SZ   (NT * 1 * 64 * 8)          // 6656
#define W1F_OFF  (W0F_OFF + W0F_SZ)
#define W1F_SZ   (NT * 7 * 64 * 8)          // 46592
#define W2F_OFF  (W1F_OFF + W1F_SZ)
#define W2F_SZ   (NT * 7 * 64 * 8)
#define WS_FRAGS (W2F_OFF + W2F_SZ)         // 99840 shorts
#define FRAG_BLOCKS  ((WS_FRAGS + 255) / 256)           // 390
#define WCONV_THREADS (VOCAB / 8)                       // 125,000
#define WCONV_BLOCKS ((WCONV_THREADS + 255) / 256)      // 489
#define VCONV_THREADS (VOCAB * NFM_E / 8)               // 2,000,000 (8 floats/thread)
#define VCONV_BLOCKS ((VCONV_THREADS + 255) / 256)      // 7813

__global__ __launch_bounds__(256)
void nfm_prep_kernel(const float* __restrict__ v,
                     const float* __restrict__ w,
                     const float* __restrict__ w0,
                     const float* __restrict__ w1,
                     const float* __restrict__ w2,
                     unsigned char* __restrict__ wsb)
{
    if (blockIdx.x < FRAG_BLOCKS) {
        const int idx = blockIdx.x * 256 + threadIdx.x;
        if (idx >= WS_FRAGS) return;
        float val;
        if (idx < W1F_OFF) {
            const int rem = idx;
            const int j = rem & 7, lane = (rem >> 3) & 63, tile = rem >> 9;
            const int k = (lane >> 4) * 8 + j;
            const int n = tile * 16 + (lane & 15);
            val = (k < NFM_E && n < NFM_H) ? w0[k * NFM_H + n] : 0.f;
        } else if (idx < W2F_OFF) {
            const int rem = idx - W1F_OFF;
            const int j = rem & 7, lane = (rem >> 3) & 63;
            const int kt = rem >> 9;
            const int ks = kt % 7, tile = kt / 7;
            const int k = ks * 32 + (lane >> 4) * 8 + j;
            const int n = tile * 16 + (lane & 15);
            val = (k < NFM_H && n < NFM_H) ? w1[k * NFM_H + n] : 0.f;
        } else {
            const int rem = idx - W2F_OFF;
            const int j = rem & 7, lane = (rem >> 3) & 63;
            const int kt = rem >> 9;
            const int ks = kt % 7, tile = kt / 7;
            const int k = ks * 32 + (lane >> 4) * 8 + j;
            const int n = tile * 16 + (lane & 15);
            val = (k < NFM_H && n < NFM_H) ? w2[k * NFM_H + n] : 0.f;
        }
        ((short*)(wsb + FRAG_BYTE_OFF))[idx] = f2bf(val);
    } else if (blockIdx.x < FRAG_BLOCKS + WCONV_BLOCKS) {
        const int t = (blockIdx.x - FRAG_BLOCKS) * 256 + threadIdx.x;
        if (t >= WCONV_THREADS) return;
        const int base = t * 8;
        const float4 a = *(const float4*)&w[base];
        const float4 b = *(const float4*)&w[base + 4];
        unsigned char o[8];
        o[0] = f_to_fp8(a.x * WSCALE); o[1] = f_to_fp8(a.y * WSCALE);
        o[2] = f_to_fp8(a.z * WSCALE); o[3] = f_to_fp8(a.w * WSCALE);
        o[4] = f_to_fp8(b.x * WSCALE); o[5] = f_to_fp8(b.y * WSCALE);
        o[6] = f_to_fp8(b.z * WSCALE); o[7] = f_to_fp8(b.w * WSCALE);
        *(uint2*)&wsb[W8_BYTE_OFF + base] = *(const uint2*)o;
    } else {
        const int t = (blockIdx.x - FRAG_BLOCKS - WCONV_BLOCKS) * 256 + threadIdx.x;
        if (t >= VCONV_THREADS) return;
        const long base = (long)t * 8;
        const float4 a = *(const float4*)&v[base];
        const float4 b = *(const float4*)&v[base + 4];
        unsigned char o[8];
        o[0] = f_to_fp8(a.x * WSCALE); o[1] = f_to_fp8(a.y * WSCALE);
        o[2] = f_to_fp8(a.z * WSCALE); o[3] = f_to_fp8(a.w * WSCALE);
        o[4] = f_to_fp8(b.x * WSCALE); o[5] = f_to_fp8(b.y * WSCALE);
        o[6] = f_to_fp8(b.z * WSCALE); o[7] = f_to_fp8(b.w * WSCALE);
        *(uint2*)&wsb[base] = *(const uint2*)o;
    }
}

__global__ __launch_bounds__(256, 8)
void nfm_main_kernel(
    const int*   __restrict__ feat_ids,   // [B,F]
    const float* __restrict__ feat_vals,  // [B,F]
    const float* __restrict__ bglob,      // [1]
    const float* __restrict__ b0,
    const float* __restrict__ b1,
    const float* __restrict__ b2,
    const unsigned char* __restrict__ wsb, // fp8 v + fp8 w + bf16 fragments
    float* __restrict__ out)              // [B]
{
    __shared__ __attribute__((aligned(16))) short hbfA[16 * KPAD]; // 7424 B
    __shared__ __attribute__((aligned(16))) short hbfB[16 * KPAD];
    __shared__ float rowsumW[4][16];
    __shared__ float lrS[TR];

    const int tid  = threadIdx.x;
    const int row0 = blockIdx.x * TR;
    const int lane = tid & 63;
    const int wv   = tid >> 6;     // wave 0..3
    const int lq   = lane >> 4;    // quad 0..3
    const int ln   = lane & 15;

    const unsigned char* v8  = wsb;
    const unsigned char* w8  = wsb + W8_BYTE_OFF;
    const short*         Wfb = (const short*)(wsb + FRAG_BYTE_OFF);

    // ---------- gather: lane l32 owns whole fields {l32, 32+l32(<39)} ----------
    // One 16B fp8 row per (row,field): 639k total v-requests (was 2.56M).
    const int r8  = tid >> 5;              // 0..7 row within block
    const int l32 = tid & 31;
    const long rbase = (long)(row0 + r8) * NFM_F;
    const bool has2 = (l32 < 7);

    const int   id1 = feat_ids [rbase + l32];
    const float vl1 = feat_vals[rbase + l32];
    int id2 = 0; float vl2 = 0.f;
    if (has2) { id2 = feat_ids[rbase + 32 + l32]; vl2 = feat_vals[rbase + 32 + l32]; }

    uint4_t r1 = __builtin_nontemporal_load((const uint4_t*)(v8 + (long)id1 * 16));
    uint4_t r2 = {0u, 0u, 0u, 0u};
    if (has2) r2 = __builtin_nontemporal_load((const uint4_t*)(v8 + (long)id2 * 16));
    const unsigned char w1b = w8[id1];
    const unsigned char w2b = has2 ? w8[id2] : (unsigned char)0;

    // Zero both activation buffers (K-pad 200..231, dummy rows 8..15, fm pad
    // cols 16..31) while the gather loads are in flight.
    {
        short8 z8 = {0, 0, 0, 0, 0, 0, 0, 0};
        short8* pA = (short8*)hbfA;
        short8* pB = (short8*)hbfB;
        for (int i = tid; i < 464; i += 256) { pA[i] = z8; pB[i] = z8; }
    }
    __syncthreads();   // zero-fill visible before fm stores land

    // ---------- FM pooling + LR (scaled x64 domain) ----------
    {
        float xv[16], x2[16];
#pragma unroll
        for (int e = 0; e < 16; ++e) { xv[e] = 0.f; x2[e] = 0.f; }
#pragma unroll
        for (int d = 0; d < 4; ++d) {
            const floatx4 ve = cvt4_fp8(r1[d]);
#pragma unroll
            for (int s = 0; s < 4; ++s) {
                const float t = vl1 * ve[s];
                xv[d * 4 + s] += t;
                x2[d * 4 + s] = fmaf(t, t, x2[d * 4 + s]);
            }
        }
#pragma unroll
        for (int d = 0; d < 4; ++d) {
            const floatx4 ve = cvt4_fp8(r2[d]);
#pragma unroll
            for (int s = 0; s < 4; ++s) {
                const float t = vl2 * ve[s];
                xv[d * 4 + s] += t;
                x2[d * 4 + s] = fmaf(t, t, x2[d * 4 + s]);
            }
        }
        float lr = vl1 * cvt1_fp8(w1b) + vl2 * cvt1_fp8(w2b);

        // reduce 33 values over the 32 lanes of this row
#pragma unroll
        for (int off = 1; off <= 16; off <<= 1) {
#pragma unroll
            for (int e = 0; e < 16; ++e) {
                xv[e] += __shfl_xor(xv[e], off, 32);
                x2[e] += __shfl_xor(x2[e], off, 32);
            }
            lr += __shfl_xor(lr, off, 32);
        }
        if (l32 < 4) {
            short4_t fm4;
#pragma unroll
            for (int c = 0; c < 4; ++c) {
                const int e = l32 * 4 + c;
                fm4[c] = f2bf(0.5f * (xv[e] * xv[e] - x2[e]) * FMSC);
            }
            *(short4_t*)&hbfB[r8 * KPAD + l32 * 4] = fm4;
        }
        if (l32 == 0) lrS[r8] = lr * WISCALE;
    }
    __syncthreads();

    // ---------- L0: fm(bf16, K=32) @ W0f -> hbfA ----------
    {
        const short8 af = *(const short8*)&hbfB[ln * KPAD + lq * 8];
        const short* Wf = Wfb + W0F_OFF;
        for (int t = wv; t < NT; t += 4) {
            const int n = t * 16 + ln;
            const float bj = (n < NFM_H) ? b0[n] : 0.f;
            floatx4 acc = {bj, bj, bj, bj};
            const short8 bf = *(const short8*)&Wf[(t * 64 + lane) * 8];
            acc = __builtin_amdgcn_mfma_f32_16x16x32_bf16(af, bf, acc, 0, 0, 0);
#pragma unroll
            for (int rg = 0; rg < 4; ++rg)          // n>=200 computes exact 0
                hbfA[(lq * 4 + rg) * KPAD + n] = f2bf(fmaxf(acc[rg], 0.f));
        }
    }
    __syncthreads();

    // ---------- L1: hbfA @ W1f -> hbfB ----------
    {
        short8 af[7];
#pragma unroll
        for (int ks = 0; ks < 7; ++ks)
            af[ks] = *(const short8*)&hbfA[ln * KPAD + ks * 32 + lq * 8];
        const short* Wf = Wfb + W1F_OFF;
        for (int t = wv; t < NT; t += 4) {
            const int n = t * 16 + ln;
            const float bj = (n < NFM_H) ? b1[n] : 0.f;
            floatx4 acc = {bj, bj, bj, bj};
#pragma unroll
            for (int ks = 0; ks < 7; ++ks) {
                const short8 bf = *(const short8*)&Wf[((t * 7 + ks) * 64 + lane) * 8];
                acc = __builtin_amdgcn_mfma_f32_16x16x32_bf16(af[ks], bf, acc, 0, 0, 0);
            }
#pragma unroll
            for (int rg = 0; rg < 4; ++rg)
                hbfB[(lq * 4 + rg) * KPAD + n] = f2bf(fmaxf(acc[rg], 0.f));
        }
    }
    __syncthreads();

    // ---------- L2: hbfB @ W2f -> row sums (no materialization) ----------
    {
        short8 af[7];
#pragma unroll
        for (int ks = 0; ks < 7; ++ks)
            af[ks] = *(const short8*)&hbfB[ln * KPAD + ks * 32 + lq * 8];
        const short* Wf = Wfb + W2F_OFF;
        float rs[4] = {0.f, 0.f, 0.f, 0.f};
        for (int t = wv; t < NT; t += 4) {
            const int n = t * 16 + ln;
            const float bj = (n < NFM_H) ? b2[n] : 0.f;
            floatx4 acc = {bj, bj, bj, bj};
#pragma unroll
            for (int ks = 0; ks < 7; ++ks) {
                const short8 bf = *(const short8*)&Wf[((t * 7 + ks) * 64 + lane) * 8];
                acc = __builtin_amdgcn_mfma_f32_16x16x32_bf16(af[ks], bf, acc, 0, 0, 0);
            }
#pragma unroll
            for (int rg = 0; rg < 4; ++rg)
                rs[rg] += fmaxf(acc[rg], 0.f);       // n>=200 adds exact 0
        }
#pragma unroll
        for (int off = 8; off >= 1; off >>= 1)
#pragma unroll
            for (int rg = 0; rg < 4; ++rg)
                rs[rg] += __shfl_xor(rs[rg], off, 16);
        if (ln == 0)
#pragma unroll
            for (int rg = 0; rg < 4; ++rg)
                rowsumW[wv][lq * 4 + rg] = rs[rg];
    }
    __syncthreads();

    // ---------- epilogue (rows 0..7 are real) ----------
    if (tid < TR) {
        const float s = rowsumW[0][tid] + rowsumW[1][tid]
                      + rowsumW[2][tid] + rowsumW[3][tid];
        const float logit = lrS[tid] + bglob[0] + s;
        out[row0 + tid] = 1.f / (1.f + expf(-logit));
    }
}

extern "C" void kernel_launch(void* const* d_in, const int* in_sizes, int n_in,
                              void* d_out, int out_size, void* d_ws, size_t ws_size,
                              hipStream_t stream) {
    const int*   feat_ids  = (const int*)  d_in[0];
    const float* feat_vals = (const float*)d_in[1];
    const float* w   = (const float*)d_in[2];
    const float* v   = (const float*)d_in[3];
    const float* b   = (const float*)d_in[4];
    const float* w0  = (const float*)d_in[5];
    const float* b0  = (const float*)d_in[6];
    const float* w1  = (const float*)d_in[7];
    const float* b1  = (const float*)d_in[8];
    const float* w2  = (const float*)d_in[9];
    const float* b2  = (const float*)d_in[10];
    float* out = (float*)d_out;
    unsigned char* wsb = (unsigned char*)d_ws;   // needs ~17.2 MB

    hipLaunchKernelGGL(nfm_prep_kernel,
                       dim3(FRAG_BLOCKS + WCONV_BLOCKS + VCONV_BLOCKS), dim3(256),
                       0, stream, v, w, w0, w1, w2, wsb);
    hipLaunchKernelGGL(nfm_main_kernel, dim3(NFM_B / TR), dim3(256), 0, stream,
                       feat_ids, feat_vals, b, b0, b1, b2, wsb, out);
}

// Round 10
// 140.447 us; speedup vs baseline: 1.2777x; 1.2777x over previous
//
#include <hip/hip_runtime.h>
#include <math.h>

#define NFM_B 16384
#define NFM_F 39
#define NFM_E 16
#define NFM_H 200
#define TR    8           // rows per block (MFMA M=16 tile, rows 8..15 zero)
#define KPAD  232         // padded K row stride (shorts); 464B, 16B-aligned
#define NT    13          // n-tiles of 16 (208 >= 200)
#define VOCAB 1000000
#define WSCALE  64.0f     // w stored as fp8(w*64): lifts N(0,0.01) into e4m3 range
#define WISCALE (1.0f / 64.0f)

typedef short short8   __attribute__((ext_vector_type(8)));   // 8 bf16 = 4 VGPRs
typedef short short4_t __attribute__((ext_vector_type(4)));
typedef float floatx4  __attribute__((ext_vector_type(4)));

__device__ __forceinline__ short f2bf(float x) {   // fp32 -> bf16 RNE
    union { float f; unsigned u; } a; a.f = x;
    unsigned r = a.u + 0x7FFF + ((a.u >> 16) & 1);
    return (short)(r >> 16);
}

// fp8 e4m3fn (OCP): 1-4-3, bias 7, max 448, no inf  (encoder, RNE)
__device__ __forceinline__ unsigned char f_to_fp8(float x) {
    union { float f; unsigned u; } a; a.f = fabsf(x);
    const unsigned s = (x < 0.f) ? 0x80u : 0u;
    int e = (int)((a.u >> 23) & 255) - 127;
    if (a.f == 0.f) return (unsigned char)s;
    if (e < -6) {                          // subnormal target: quantum 2^-9
        int m = (int)rintf(a.f * 512.f);   // RNE
        if (m >= 8) return (unsigned char)(s | (1u << 3));
        return (unsigned char)(s | (unsigned)m);
    }
    unsigned m23 = a.u & 0x7FFFFF;
    unsigned m3  = m23 >> 20, rem = m23 & 0xFFFFF;
    if (rem > 0x80000 || (rem == 0x80000 && (m3 & 1))) m3++;
    if (m3 == 8) { m3 = 0; e++; }
    if (e > 8) { e = 8; m3 = 6; }          // clamp to 448
    return (unsigned char)(s | ((unsigned)(e + 7) << 3) | m3);
}
__device__ __forceinline__ float fp8_sw_decode(unsigned char b) {
    const unsigned s = (b >> 7) & 1, e = (b >> 3) & 15, m = b & 7;
    union { unsigned u; float f; } a;
    if (e == 0) { a.f = (float)m * 0.001953125f; }
    else        { a.u = ((e - 7 + 127) << 23) | (m << 20); }
    if (s) a.f = -a.f;
    return a.f;
}
#if defined(__has_builtin) && __has_builtin(__builtin_amdgcn_cvt_f32_fp8)
__device__ __forceinline__ float cvt1_fp8(unsigned char b) {
    return __builtin_amdgcn_cvt_f32_fp8((int)(unsigned)b, 0);
}
#else
__device__ __forceinline__ float cvt1_fp8(unsigned char b) { return fp8_sw_decode(b); }
#endif

// d_ws layout:
//   bytes  [0, VOCAB)           : w table as fp8 e4m3 of (w*64)  -- 1 MB
//   shorts [FRAG_OFF, +WS_FRAGS): W0/W1/W2 bf16 B-fragments
// (No v table in ws: R5/R9 proved per-launch table builds cost more in
//  prep reads + dirty-L2 writebacks than the gather saves.)
#define FRAG_OFF (VOCAB / 2)                // shorts; byte 1,000,000 (16B-aligned)
#define W0F_OFF  0
#define W0F_SZ   (NT * 1 * 64 * 8)          // 6656
#define W1F_OFF  (W0F_OFF + W0F_SZ)
#define W1F_SZ   (NT * 7 * 64 * 8)          // 46592
#define W2F_OFF  (W1F_OFF + W1F_SZ)
#define W2F_SZ   (NT * 7 * 64 * 8)
#define WS_FRAGS (W2F_OFF + W2F_SZ)         // 99840 shorts
#define FRAG_BLOCKS  ((WS_FRAGS + 255) / 256)           // 390
#define WCONV_THREADS (VOCAB / 8)                       // 125,000
#define WCONV_BLOCKS ((WCONV_THREADS + 255) / 256)      // 489

__global__ __launch_bounds__(256)
void nfm_prep_kernel(const float* __restrict__ w,
                     const float* __restrict__ w0,
                     const float* __restrict__ w1,
                     const float* __restrict__ w2,
                     short* __restrict__ ws)
{
    if (blockIdx.x < FRAG_BLOCKS) {
        const int idx = blockIdx.x * 256 + threadIdx.x;
        if (idx >= WS_FRAGS) return;
        float val;
        if (idx < W1F_OFF) {
            const int rem = idx;
            const int j = rem & 7, lane = (rem >> 3) & 63, tile = rem >> 9;
            const int k = (lane >> 4) * 8 + j;
            const int n = tile * 16 + (lane & 15);
            val = (k < NFM_E && n < NFM_H) ? w0[k * NFM_H + n] : 0.f;
        } else if (idx < W2F_OFF) {
            const int rem = idx - W1F_OFF;
            const int j = rem & 7, lane = (rem >> 3) & 63;
            const int kt = rem >> 9;
            const int ks = kt % 7, tile = kt / 7;
            const int k = ks * 32 + (lane >> 4) * 8 + j;
            const int n = tile * 16 + (lane & 15);
            val = (k < NFM_H && n < NFM_H) ? w1[k * NFM_H + n] : 0.f;
        } else {
            const int rem = idx - W2F_OFF;
            const int j = rem & 7, lane = (rem >> 3) & 63;
            const int kt = rem >> 9;
            const int ks = kt % 7, tile = kt / 7;
            const int k = ks * 32 + (lane >> 4) * 8 + j;
            const int n = tile * 16 + (lane & 15);
            val = (k < NFM_H && n < NFM_H) ? w2[k * NFM_H + n] : 0.f;
        }
        ws[FRAG_OFF + idx] = f2bf(val);
    } else {
        const int t = (blockIdx.x - FRAG_BLOCKS) * 256 + threadIdx.x;
        if (t >= WCONV_THREADS) return;
        const int base = t * 8;
        const float4 a = *(const float4*)&w[base];
        const float4 b = *(const float4*)&w[base + 4];
        unsigned char o[8];
        o[0] = f_to_fp8(a.x * WSCALE); o[1] = f_to_fp8(a.y * WSCALE);
        o[2] = f_to_fp8(a.z * WSCALE); o[3] = f_to_fp8(a.w * WSCALE);
        o[4] = f_to_fp8(b.x * WSCALE); o[5] = f_to_fp8(b.y * WSCALE);
        o[6] = f_to_fp8(b.z * WSCALE); o[7] = f_to_fp8(b.w * WSCALE);
        *(uint2*)&((unsigned char*)ws)[base] = *(const uint2*)o;
    }
}

__global__ __launch_bounds__(256, 8)
void nfm_main_kernel(
    const int*   __restrict__ feat_ids,   // [B,F]
    const float* __restrict__ feat_vals,  // [B,F]
    const float* __restrict__ v,          // [VOCAB,16] fp32
    const float* __restrict__ bglob,      // [1]
    const float* __restrict__ b0,
    const float* __restrict__ b1,
    const float* __restrict__ b2,
    const short* __restrict__ ws,         // fp8 w table + bf16 weight fragments
    float* __restrict__ out)              // [B]
{
    __shared__ __attribute__((aligned(16))) short hbfA[16 * KPAD]; // 7424 B
    __shared__ __attribute__((aligned(16))) short hbfB[16 * KPAD];
    __shared__ float rowsumW[4][16];
    __shared__ float lrS[TR];

    const int tid  = threadIdx.x;
    const int row0 = blockIdx.x * TR;
    const int lane = tid & 63;
    const int wv   = tid >> 6;     // wave 0..3
    const int lq   = lane >> 4;    // quad 0..3
    const int ln   = lane & 15;

    const unsigned char* w8  = (const unsigned char*)ws;   // fp8 w table
    const short*         Wfb = ws + FRAG_OFF;              // weight fragments

    // ---------- issue all gather loads up front (plain loads: L2 allocation
    // captures duplicate-id reuse; nt hint measurably hurt in R7/R9) ----------
    const int r8  = tid >> 5;              // 0..7 row within block
    const int l32 = tid & 31;
    const int fs  = l32 >> 2, eg = l32 & 3;
    const long rbase = (long)(row0 + r8) * NFM_F;

    int   idv[5]; float vlv[5];
#pragma unroll
    for (int it = 0; it < 5; ++it) {
        const int f = fs + it * 8;         // fs=7,it=4 -> 39 OOB (pad)
        const bool ok = f < NFM_F;
        idv[it] = ok ? feat_ids [rbase + f] : 0;
        vlv[it] = ok ? feat_vals[rbase + f] : 0.f;
    }
    floatx4 ve[5];
#pragma unroll
    for (int it = 0; it < 5; ++it)
        ve[it] = *(const floatx4*)&v[(long)idv[it] * NFM_E + eg * 4];
    // LR w-gather: eg==0 lanes reuse idv/vlv (fields fs+8*it cover 0..39)
    float lr = 0.f;
    if (eg == 0) {
#pragma unroll
        for (int it = 0; it < 5; ++it)
            lr += vlv[it] * cvt1_fp8(w8[idv[it]]);
        lr *= WISCALE;
    }

    // Zero both activation buffers (K-pad 200..231, dummy rows 8..15, fm pad
    // cols 16..31) while the gather loads are in flight.
    {
        short8 z8 = {0, 0, 0, 0, 0, 0, 0, 0};
        short8* pA = (short8*)hbfA;
        short8* pB = (short8*)hbfB;
        for (int i = tid; i < 464; i += 256) { pA[i] = z8; pB[i] = z8; }
    }
    __syncthreads();   // zero-fill visible before fm stores land

    // ---------- FM pooling + LR reduce ----------
    {
        floatx4 xv = {0.f, 0.f, 0.f, 0.f}, x2 = {0.f, 0.f, 0.f, 0.f};
#pragma unroll
        for (int it = 0; it < 5; ++it) {
            const float val = vlv[it];
            const float t0 = val * ve[it][0], t1 = val * ve[it][1];
            const float t2 = val * ve[it][2], t3 = val * ve[it][3];
            xv[0] += t0; xv[1] += t1; xv[2] += t2; xv[3] += t3;
            x2[0] = fmaf(t0, t0, x2[0]); x2[1] = fmaf(t1, t1, x2[1]);
            x2[2] = fmaf(t2, t2, x2[2]); x2[3] = fmaf(t3, t3, x2[3]);
        }
#pragma unroll
        for (int off = 4; off <= 16; off <<= 1) {
#pragma unroll
            for (int c = 0; c < 4; ++c) {
                xv[c] += __shfl_xor(xv[c], off, 32);
                x2[c] += __shfl_xor(x2[c], off, 32);
            }
        }
        if (fs == 0) {
            short4_t fm4;
#pragma unroll
            for (int c = 0; c < 4; ++c)
                fm4[c] = f2bf(0.5f * (xv[c] * xv[c] - x2[c]));
            *(short4_t*)&hbfB[r8 * KPAD + eg * 4] = fm4;
        }
        // lr is nonzero only on eg==0 lanes; xor over fs offsets sums them
#pragma unroll
        for (int off = 4; off <= 16; off <<= 1)
            lr += __shfl_xor(lr, off, 32);
        if (l32 == 0) lrS[r8] = lr;
    }
    __syncthreads();

    // ---------- L0: fm(bf16, K=32) @ W0f -> hbfA ----------
    {
        const short8 af = *(const short8*)&hbfB[ln * KPAD + lq * 8];
        const short* Wf = Wfb + W0F_OFF;
        for (int t = wv; t < NT; t += 4) {
            const int n = t * 16 + ln;
            const float bj = (n < NFM_H) ? b0[n] : 0.f;
            floatx4 acc = {bj, bj, bj, bj};
            const short8 bf = *(const short8*)&Wf[(t * 64 + lane) * 8];
            acc = __builtin_amdgcn_mfma_f32_16x16x32_bf16(af, bf, acc, 0, 0, 0);
#pragma unroll
            for (int rg = 0; rg < 4; ++rg)          // n>=200 computes exact 0
                hbfA[(lq * 4 + rg) * KPAD + n] = f2bf(fmaxf(acc[rg], 0.f));
        }
    }
    __syncthreads();

    // ---------- L1: hbfA @ W1f -> hbfB ----------
    {
        short8 af[7];
#pragma unroll
        for (int ks = 0; ks < 7; ++ks)
            af[ks] = *(const short8*)&hbfA[ln * KPAD + ks * 32 + lq * 8];
        const short* Wf = Wfb + W1F_OFF;
        for (int t = wv; t < NT; t += 4) {
            const int n = t * 16 + ln;
            const float bj = (n < NFM_H) ? b1[n] : 0.f;
            floatx4 acc = {bj, bj, bj, bj};
#pragma unroll
            for (int ks = 0; ks < 7; ++ks) {
                const short8 bf = *(const short8*)&Wf[((t * 7 + ks) * 64 + lane) * 8];
                acc = __builtin_amdgcn_mfma_f32_16x16x32_bf16(af[ks], bf, acc, 0, 0, 0);
            }
#pragma unroll
            for (int rg = 0; rg < 4; ++rg)
                hbfB[(lq * 4 + rg) * KPAD + n] = f2bf(fmaxf(acc[rg], 0.f));
        }
    }
    __syncthreads();

    // ---------- L2: hbfB @ W2f -> row sums (no materialization) ----------
    {
        short8 af[7];
#pragma unroll
        for (int ks = 0; ks < 7; ++ks)
            af[ks] = *(const short8*)&hbfB[ln * KPAD + ks * 32 + lq * 8];
        const short* Wf = Wfb + W2F_OFF;
        float rs[4] = {0.f, 0.f, 0.f, 0.f};
        for (int t = wv; t < NT; t += 4) {
            const int n = t * 16 + ln;
            const float bj = (n < NFM_H) ? b2[n] : 0.f;
            floatx4 acc = {bj, bj, bj, bj};
#pragma unroll
            for (int ks = 0; ks < 7; ++ks) {
                const short8 bf = *(const short8*)&Wf[((t * 7 + ks) * 64 + lane) * 8];
                acc = __builtin_amdgcn_mfma_f32_16x16x32_bf16(af[ks], bf, acc, 0, 0, 0);
            }
#pragma unroll
            for (int rg = 0; rg < 4; ++rg)
                rs[rg] += fmaxf(acc[rg], 0.f);       // n>=200 adds exact 0
        }
#pragma unroll
        for (int off = 8; off >= 1; off >>= 1)
#pragma unroll
            for (int rg = 0; rg < 4; ++rg)
                rs[rg] += __shfl_xor(rs[rg], off, 16);
        if (ln == 0)
#pragma unroll
            for (int rg = 0; rg < 4; ++rg)
                rowsumW[wv][lq * 4 + rg] = rs[rg];
    }
    __syncthreads();

    // ---------- epilogue (rows 0..7 are real) ----------
    if (tid < TR) {
        const float s = rowsumW[0][tid] + rowsumW[1][tid]
                      + rowsumW[2][tid] + rowsumW[3][tid];
        const float logit = lrS[tid] + bglob[0] + s;
        out[row0 + tid] = 1.f / (1.f + expf(-logit));
    }
}

extern "C" void kernel_launch(void* const* d_in, const int* in_sizes, int n_in,
                              void* d_out, int out_size, void* d_ws, size_t ws_size,
                              hipStream_t stream) {
    const int*   feat_ids  = (const int*)  d_in[0];
    const float* feat_vals = (const float*)d_in[1];
    const float* w   = (const float*)d_in[2];
    const float* v   = (const float*)d_in[3];
    const float* b   = (const float*)d_in[4];
    const float* w0  = (const float*)d_in[5];
    const float* b0  = (const float*)d_in[6];
    const float* w1  = (const float*)d_in[7];
    const float* b1  = (const float*)d_in[8];
    const float* w2  = (const float*)d_in[9];
    const float* b2  = (const float*)d_in[10];
    float* out = (float*)d_out;
    short* ws  = (short*)d_ws;   // needs 1 MB (fp8 w) + 200 KB (frags)

    hipLaunchKernelGGL(nfm_prep_kernel, dim3(FRAG_BLOCKS + WCONV_BLOCKS), dim3(256),
                       0, stream, w, w0, w1, w2, ws);
    hipLaunchKernelGGL(nfm_main_kernel, dim3(NFM_B / TR), dim3(256), 0, stream,
                       feat_ids, feat_vals, v, b, b0, b1, b2, ws, out);
}